// Round 2
// 414.880 us; speedup vs baseline: 1.1156x; 1.1156x over previous
//
#include <hip/hip_runtime.h>
#include <stdint.h>

#define T_FULL 2048
#define NB_TOT 1025
#define KBANDS 36
#define EMBED 128
#define MAXF 130
#define KSMAX 5
#define EPSV 1e-5f
#define ESTRIDE (KBANDS * T_FULL)  // 73728 floats between e-rows of out

typedef __attribute__((ext_vector_type(8))) short short8;
typedef __attribute__((ext_vector_type(4))) float floatx4;
typedef __attribute__((ext_vector_type(2))) float floatx2;
typedef __attribute__((ext_vector_type(4))) uint32_t uint32x4;

__device__ __forceinline__ void band_info(int band, int& nb, int& start) {
  if (band < 20)      { nb = 16; start = band << 4; }
  else if (band < 30) { nb = 32; start = 320 + ((band - 20) << 5); }
  else if (band < 35) { nb = 64; start = 640 + ((band - 30) << 6); }
  else                { nb = 65; start = 960; }
}

__device__ __forceinline__ unsigned short f2bf(float x) {
  union { float f; uint32_t u; } c; c.f = x;
  return (unsigned short)((c.u + 0x7FFFu + ((c.u >> 16) & 1u)) >> 16);
}

// ---- prologue (one launch, two roles):
//  y < 16 : S[k,e] = sum_f W*gamma, BB[k,e] = b + sum_f W*beta   (wave per (band,e))
//  y >= 16: repack A'[band][kk][ef][lane] = MFMA A-fragment of (W*gamma) in bf16,
//           so the hot loop reads A as fully-contiguous 1KB/instr from L2.
__global__ void __launch_bounds__(512) prolog_kernel(
    const float* __restrict__ W, const float* __restrict__ gamma,
    const float* __restrict__ beta, const float* __restrict__ bvec,
    unsigned short* __restrict__ A, float* __restrict__ S, float* __restrict__ BB)
{
  int band = blockIdx.x;
  int nb, start; band_info(band, nb, start);
  int f = nb * 2;
  int w = threadIdx.x >> 6, lane = threadIdx.x & 63;

  if (blockIdx.y < 16) {
    int e = blockIdx.y * 8 + w;
    const float* wrow = W + ((size_t)band * EMBED + e) * MAXF;
    const float* grow = gamma + (size_t)band * MAXF;
    const float* brow = beta + (size_t)band * MAXF;
    float s = 0.f, bb = 0.f;
    for (int i = lane; i < f; i += 64) {
      float wv = wrow[i];
      s  += wv * grow[i];
      bb += wv * brow[i];
    }
    #pragma unroll
    for (int off = 32; off > 0; off >>= 1) {
      s  += __shfl_down(s, off);
      bb += __shfl_down(bb, off);
    }
    if (lane == 0) {
      S[band * EMBED + e]  = s;
      BB[band * EMBED + e] = bvec[band * EMBED + e] + bb;
    }
  } else {
    int kk = blockIdx.y - 16;
    int ksteps = (f + 31) >> 5;
    if (kk >= ksteps) return;
    int ef = w;                              // 0..7 (e-fragment)
    int e = ef * 16 + (lane & 15);
    int k0 = kk * 32 + (lane >> 4) * 8;
    const float* wrow = W + ((size_t)band * EMBED + e) * MAXF;
    const float* grow = gamma + (size_t)band * MAXF;
    uint32_t u[4];
    #pragma unroll
    for (int p = 0; p < 4; ++p) {
      int ka = k0 + 2 * p, kb = ka + 1;
      float va = (ka < f) ? wrow[ka] * grow[ka] : 0.f;
      float vb = (kb < f) ? wrow[kb] * grow[kb] : 0.f;
      u[p] = (uint32_t)f2bf(va) | ((uint32_t)f2bf(vb) << 16);
    }
    uint32x4 frag = {u[0], u[1], u[2], u[3]};
    *((uint32x4*)A + (((size_t)band * KSMAX + kk) * 8 + ef) * 64 + lane) = frag;
  }
}

// ---- main: zero LDS, zero barriers. Block = (128 t-tile, band, b); wave w owns
// t in [t0+32w, t0+32w+32) x all 128 e. B-fragments load HBM->reg (4x128B
// segments per instr), LN stats accumulate in-reg and reduce via shfl_xor over
// the quad bits; A-fragments stream from the repacked L2-hot A'.
template<int NB, int KS>
__device__ __forceinline__ void band_impl(
    const float* __restrict__ spec, const unsigned short* __restrict__ A,
    const float* __restrict__ S, const float* __restrict__ BB,
    float* __restrict__ out, int band, int start)
{
  int tid = threadIdx.x;
  int w = tid >> 6, lane = tid & 63;
  int lane16 = lane & 15, quad = lane >> 4;
  int b = blockIdx.z;
  int t0 = blockIdx.x * 128 + w * 32;

  floatx4 acc[8][2];
  #pragma unroll
  for (int ef = 0; ef < 8; ++ef) {
    acc[ef][0] = floatx4{0.f, 0.f, 0.f, 0.f};
    acc[ef][1] = floatx4{0.f, 0.f, 0.f, 0.f};
  }

  const floatx2* sp = (const floatx2*)spec +
      ((size_t)(b * NB_TOT + start) * T_FULL + t0 + lane16);
  const short8* ap = (const short8*)A + ((size_t)band * KSMAX * 8) * 64 + lane;

  float s0 = 0.f, q0 = 0.f, s1 = 0.f, q1 = 0.f;
  #pragma unroll 2
  for (int kk = 0; kk < KS; ++kk) {
    union { short8 s8; uint32_t u[4]; } b0, b1;
    #pragma unroll
    for (int i = 0; i < 4; ++i) {
      int bin = kk * 16 + quad * 4 + i;
      floatx2 v0 = floatx2{0.f, 0.f}, v1 = floatx2{0.f, 0.f};
      if ((NB & 15) == 0 || bin < NB) {      // folds away except NB=65 last step
        v0 = sp[(size_t)bin * T_FULL];
        v1 = sp[(size_t)bin * T_FULL + 16];
      }
      s0 += v0.x + v0.y; q0 += v0.x * v0.x + v0.y * v0.y;
      s1 += v1.x + v1.y; q1 += v1.x * v1.x + v1.y * v1.y;
      b0.u[i] = (uint32_t)f2bf(v0.x) | ((uint32_t)f2bf(v0.y) << 16);
      b1.u[i] = (uint32_t)f2bf(v1.x) | ((uint32_t)f2bf(v1.y) << 16);
    }
    #pragma unroll
    for (int ef = 0; ef < 8; ++ef) {
      short8 a = ap[(kk * 8 + ef) * 64];     // contiguous 1KB/instr, L2-hot
      acc[ef][0] = __builtin_amdgcn_mfma_f32_16x16x32_bf16(a, b0.s8, acc[ef][0], 0, 0, 0);
      acc[ef][1] = __builtin_amdgcn_mfma_f32_16x16x32_bf16(a, b1.s8, acc[ef][1], 0, 0, 0);
    }
  }

  // reduce stats over the 4 quads (f-dimension); results land in every lane
  s0 += __shfl_xor(s0, 16); q0 += __shfl_xor(q0, 16);
  s1 += __shfl_xor(s1, 16); q1 += __shfl_xor(q1, 16);
  s0 += __shfl_xor(s0, 32); q0 += __shfl_xor(q0, 32);
  s1 += __shfl_xor(s1, 32); q1 += __shfl_xor(q1, 32);

  constexpr float inv_f = 1.0f / (float)(2 * NB);
  float mu0 = s0 * inv_f, mu1 = s1 * inv_f;
  float rs0 = rsqrtf(q0 * inv_f - mu0 * mu0 + EPSV);
  float rs1 = rsqrtf(q1 * inv_f - mu1 * mu1 + EPSV);

  // epilogue: y = rstd*(G - mu*S) + BB ; C-layout col=lane16 (=t), row=quad*4+r (=e)
  size_t obase = ((size_t)(b * EMBED) * KBANDS + band) * T_FULL + t0 + lane16;
  const float* Sb = S + band * EMBED + quad * 4;
  const float* Bb = BB + band * EMBED + quad * 4;
  #pragma unroll
  for (int ef = 0; ef < 8; ++ef) {
    floatx4 Sv = *(const floatx4*)(Sb + ef * 16);
    floatx4 Bv = *(const floatx4*)(Bb + ef * 16);
    size_t eb = obase + (size_t)(ef * 16 + quad * 4) * ESTRIDE;
    #pragma unroll
    for (int r = 0; r < 4; ++r) {
      out[eb + (size_t)r * ESTRIDE]      = rs0 * (acc[ef][0][r] - mu0 * Sv[r]) + Bv[r];
      out[eb + (size_t)r * ESTRIDE + 16] = rs1 * (acc[ef][1][r] - mu1 * Sv[r]) + Bv[r];
    }
  }
}

__global__ void __launch_bounds__(256, 3) band_kernel(
    const float* __restrict__ spec, const unsigned short* __restrict__ A,
    const float* __restrict__ S, const float* __restrict__ BB,
    float* __restrict__ out)
{
  int band = blockIdx.y;
  int nb_unused, start; band_info(band, nb_unused, start);
  if (band < 20)      band_impl<16, 1>(spec, A, S, BB, out, band, start);
  else if (band < 30) band_impl<32, 2>(spec, A, S, BB, out, band, start);
  else if (band < 35) band_impl<64, 4>(spec, A, S, BB, out, band, start);
  else                band_impl<65, 5>(spec, A, S, BB, out, band, start);
}

extern "C" void kernel_launch(void* const* d_in, const int* in_sizes, int n_in,
                              void* d_out, int out_size, void* d_ws, size_t ws_size,
                              hipStream_t stream) {
  const float* spec  = (const float*)d_in[0];
  const float* gamma = (const float*)d_in[1];
  const float* beta  = (const float*)d_in[2];
  const float* W     = (const float*)d_in[3];
  const float* bvec  = (const float*)d_in[4];
  float* out = (float*)d_out;

  // ws: A' bf16 [36][5][8][64][8] (1,474,560 B) | S f32 [36*128] | BB f32 [36*128]
  unsigned short* A = (unsigned short*)d_ws;
  size_t a_bytes = (size_t)KBANDS * KSMAX * 8 * 64 * 16;
  float* S  = (float*)((char*)d_ws + a_bytes);
  float* BB = S + KBANDS * EMBED;

  prolog_kernel<<<dim3(KBANDS, 21), dim3(512), 0, stream>>>(W, gamma, beta, bvec, A, S, BB);
  band_kernel<<<dim3(T_FULL / 128, KBANDS, 8), dim3(256), 0, stream>>>(spec, A, S, BB, out);
}